// Round 1
// baseline (1198.202 us; speedup 1.0000x reference)
//
#include <hip/hip_runtime.h>

// Problem constants (fixed by the reference)
#define BATCH 4
#define HH    56
#define WW    56
#define NTOK  3136    // 56*56
#define NKV   784     // 28*28
#define CD    512
#define NH    8
#define DH    64
#define SCALE 0.125f  // (512/8)^-0.5

// ---------------- workspace layout (floats) ----------------
// qbuf : [B*N, 512]          6,422,528
// scr  : im2col [3136,2048]  6,422,528  (reused later as attn out [B*N,512])
// kvb  : conv+LN out [3136,512]  1,605,632
// kvp  : kv proj [3136,1024]     3,211,264
// swt  : sr_w transposed [2048,512]  1,048,576
static const size_t OFF_Q   = 0;
static const size_t OFF_SCR = 6422528;
static const size_t OFF_KV  = 12845056;
static const size_t OFF_KVP = 14450688;
static const size_t OFF_SWT = 17661952;
// total 18,710,528 floats = ~74.9 MB

// ---- sr_w OIHW [512,512,2,2] -> [p*512+i][o]  (p = ky*2+kx) ----
__global__ void srwt_k(const float* __restrict__ w, float* __restrict__ out) {
    int idx = blockIdx.x * blockDim.x + threadIdx.x;   // over 2048*512
    int o = idx & 511;
    int rest = idx >> 9;
    int i = rest & 511;
    int p = rest >> 9;
    out[idx] = w[(((size_t)o * 512 + i) << 2) + p];
}

// ---- im2col: v [B,3136,512] -> [B*784, 2048] (p-major: p*512+i) ----
__global__ void im2col_k(const float* __restrict__ v, float* __restrict__ out) {
    int idx = blockIdx.x * blockDim.x + threadIdx.x;   // over 3136*2048
    int i = idx & 511;
    int p = (idx >> 9) & 3;
    int t = idx >> 11;                 // 0..3135  (b*784 + oy*28+ox)
    int b = t / NKV;
    int tt = t - b * NKV;
    int oy = tt / 28, ox = tt - (tt / 28) * 28;
    int ky = p >> 1, kx = p & 1;
    int y = oy * 2 + ky, x = ox * 2 + kx;
    out[idx] = v[((size_t)b * NTOK + y * WW + x) * CD + i];
}

// ---- generic fp32 GEMM: C[M,N] = A[M,K] @ B[K,N] (+bias[N]) ----
// 64x64 tile, BK=16, 256 threads, 4x4 per thread. M%64==0, N%64==0, K%16==0.
__global__ __launch_bounds__(256) void gemm64(
    const float* __restrict__ A, const float* __restrict__ Bm,
    const float* __restrict__ bias, float* __restrict__ C,
    int M, int N, int K)
{
    __shared__ float As[16][68];
    __shared__ float Bs[16][68];
    const int tid = threadIdx.x;
    const int bn = blockIdx.x * 64;
    const int bm = blockIdx.y * 64;
    const int tx = tid & 15, ty = tid >> 4;
    const int la_c = tid & 15, la_r = tid >> 4;   // A tile: col k, row
    const int lb_c = tid & 63, lb_r = tid >> 6;   // B tile
    float acc[4][4] = {};
    for (int k0 = 0; k0 < K; k0 += 16) {
        #pragma unroll
        for (int r = 0; r < 4; ++r)
            As[la_c][la_r + 16 * r] = A[(size_t)(bm + la_r + 16 * r) * K + k0 + la_c];
        #pragma unroll
        for (int r = 0; r < 4; ++r)
            Bs[lb_r + 4 * r][lb_c] = Bm[(size_t)(k0 + lb_r + 4 * r) * N + bn + lb_c];
        __syncthreads();
        #pragma unroll
        for (int kk = 0; kk < 16; ++kk) {
            float4 av = *(const float4*)&As[kk][ty * 4];
            float4 bv = *(const float4*)&Bs[kk][tx * 4];
            float a[4] = {av.x, av.y, av.z, av.w};
            float b[4] = {bv.x, bv.y, bv.z, bv.w};
            #pragma unroll
            for (int i = 0; i < 4; ++i)
                #pragma unroll
                for (int j = 0; j < 4; ++j)
                    acc[i][j] = fmaf(a[i], b[j], acc[i][j]);
        }
        __syncthreads();
    }
    #pragma unroll
    for (int i = 0; i < 4; ++i) {
        int row = bm + ty * 4 + i;
        int col = bn + tx * 4;
        float b0 = bias ? bias[col + 0] : 0.f;
        float b1 = bias ? bias[col + 1] : 0.f;
        float b2 = bias ? bias[col + 2] : 0.f;
        float b3 = bias ? bias[col + 3] : 0.f;
        float4 o = make_float4(acc[i][0] + b0, acc[i][1] + b1,
                               acc[i][2] + b2, acc[i][3] + b3);
        *(float4*)&C[(size_t)row * N + col] = o;
    }
}

// ---- LayerNorm over 512, in place. One block (256 thr) per token. ----
__global__ __launch_bounds__(256) void ln_k(float* __restrict__ x,
    const float* __restrict__ g, const float* __restrict__ bta)
{
    int t = blockIdx.x;
    float* row = x + (size_t)t * CD;
    int tid = threadIdx.x;
    float2 xv = *(float2*)&row[tid * 2];
    float s  = xv.x + xv.y;
    float s2 = xv.x * xv.x + xv.y * xv.y;
    #pragma unroll
    for (int off = 32; off > 0; off >>= 1) {
        s  += __shfl_down(s, off);
        s2 += __shfl_down(s2, off);
    }
    __shared__ float sa[4], sb[4];
    int wid = tid >> 6, lane = tid & 63;
    if (lane == 0) { sa[wid] = s; sb[wid] = s2; }
    __syncthreads();
    if (tid == 0) {
        float S = sa[0] + sa[1] + sa[2] + sa[3];
        float S2 = sb[0] + sb[1] + sb[2] + sb[3];
        sa[0] = S; sb[0] = S2;
    }
    __syncthreads();
    float mu  = sa[0] * (1.f / 512.f);
    float var = sb[0] * (1.f / 512.f) - mu * mu;
    float inv = rsqrtf(var + 1e-5f);
    float2 gv = *(const float2*)&g[tid * 2];
    float2 bv = *(const float2*)&bta[tid * 2];
    xv.x = (xv.x - mu) * inv * gv.x + bv.x;
    xv.y = (xv.y - mu) * inv * gv.y + bv.y;
    *(float2*)&row[tid * 2] = xv;
}

// ---- attention: one wave (64 thr) per (b, h, 64 q-rows); thread = 1 q-row ----
// q: [B*N,512] (head-major cols), kvp: [B*784,1024] (k | v), out: [B*N,512]
#define CHUNK 56
__global__ __launch_bounds__(64) void attn_k(
    const float* __restrict__ q, const float* __restrict__ kvp,
    float* __restrict__ out)
{
    __shared__ float Ks[CHUNK][64];
    __shared__ float Vs[CHUNK][64];
    const int qb = blockIdx.x;    // 0..48
    const int h  = blockIdx.y;    // 0..7
    const int b  = blockIdx.z;    // 0..3
    const int tid = threadIdx.x;  // 0..63
    const int r = qb * 64 + tid;
    const float* qrow = q + ((size_t)(b * NTOK + r)) * CD + h * DH;
    float qr[64];
    #pragma unroll
    for (int d4 = 0; d4 < 16; ++d4) {
        float4 t = *(const float4*)&qrow[d4 * 4];
        qr[d4*4+0] = t.x; qr[d4*4+1] = t.y; qr[d4*4+2] = t.z; qr[d4*4+3] = t.w;
    }
    float acc[64];
    #pragma unroll
    for (int d = 0; d < 64; ++d) acc[d] = 0.f;
    float denom = 0.f;
    for (int s0 = 0; s0 < NKV; s0 += CHUNK) {
        if (tid < CHUNK) {
            const float* kp = kvp + ((size_t)(b * NKV + s0 + tid)) * 1024 + h * DH;
            #pragma unroll
            for (int d4 = 0; d4 < 16; ++d4) {
                *(float4*)&Ks[tid][d4 * 4] = *(const float4*)&kp[d4 * 4];
                *(float4*)&Vs[tid][d4 * 4] = *(const float4*)&kp[512 + d4 * 4];
            }
        }
        __syncthreads();
        for (int j = 0; j < CHUNK; ++j) {
            float p0 = 0.f, p1 = 0.f, p2 = 0.f, p3 = 0.f;
            #pragma unroll
            for (int d4 = 0; d4 < 16; ++d4) {
                float4 k4 = *(const float4*)&Ks[j][d4 * 4];
                p0 = fmaf(qr[d4*4+0], k4.x, p0);
                p1 = fmaf(qr[d4*4+1], k4.y, p1);
                p2 = fmaf(qr[d4*4+2], k4.z, p2);
                p3 = fmaf(qr[d4*4+3], k4.w, p3);
            }
            float sc = (p0 + p1) + (p2 + p3);
            float p = __expf(sc * SCALE);
            denom += p;
            #pragma unroll
            for (int d4 = 0; d4 < 16; ++d4) {
                float4 v4 = *(const float4*)&Vs[j][d4 * 4];
                acc[d4*4+0] = fmaf(p, v4.x, acc[d4*4+0]);
                acc[d4*4+1] = fmaf(p, v4.y, acc[d4*4+1]);
                acc[d4*4+2] = fmaf(p, v4.z, acc[d4*4+2]);
                acc[d4*4+3] = fmaf(p, v4.w, acc[d4*4+3]);
            }
        }
        __syncthreads();
    }
    float invd = 1.f / denom;
    float* op = out + ((size_t)(b * NTOK + r)) * CD + h * DH;
    #pragma unroll
    for (int d4 = 0; d4 < 16; ++d4) {
        float4 o = make_float4(acc[d4*4+0] * invd, acc[d4*4+1] * invd,
                               acc[d4*4+2] * invd, acc[d4*4+3] * invd);
        *(float4*)&op[d4 * 4] = o;
    }
}

extern "C" void kernel_launch(void* const* d_in, const int* in_sizes, int n_in,
                              void* d_out, int out_size, void* d_ws, size_t ws_size,
                              hipStream_t stream)
{
    const float* x    = (const float*)d_in[0];
    const float* v    = (const float*)d_in[1];
    // d_in[2], d_in[3] are h,w scalars (fixed 56x56 — compiled in)
    const float* q_w  = (const float*)d_in[4];
    const float* kv_w = (const float*)d_in[5];
    const float* sr_w = (const float*)d_in[6];
    const float* sr_b = (const float*)d_in[7];
    const float* ln_g = (const float*)d_in[8];
    const float* ln_b = (const float*)d_in[9];
    const float* pj_w = (const float*)d_in[10];
    const float* pj_b = (const float*)d_in[11];
    float* out = (float*)d_out;
    float* ws  = (float*)d_ws;

    float* qbuf = ws + OFF_Q;
    float* scr  = ws + OFF_SCR;   // im2col, later attention output
    float* kvb  = ws + OFF_KV;
    float* kvp  = ws + OFF_KVP;
    float* swt  = ws + OFF_SWT;

    // 1) transpose sr_w -> [2048, 512]
    srwt_k<<<(2048 * 512) / 256, 256, 0, stream>>>(sr_w, swt);
    // 2) im2col of v -> [3136, 2048]
    im2col_k<<<(3136 * 2048) / 256, 256, 0, stream>>>(v, scr);
    // 3) SR conv as GEMM (+bias): [3136,2048]@[2048,512] -> kvb
    gemm64<<<dim3(8, 49), 256, 0, stream>>>(scr, swt, sr_b, kvb, 3136, 512, 2048);
    // 4) LayerNorm in place
    ln_k<<<3136, 256, 0, stream>>>(kvb, ln_g, ln_b);
    // 5) kv projection: [3136,512]@[512,1024] -> kvp (k | v)
    gemm64<<<dim3(16, 49), 256, 0, stream>>>(kvb, kv_w, nullptr, kvp, 3136, 1024, 512);
    // 6) q projection: [12544,512]@[512,512] -> qbuf
    gemm64<<<dim3(8, 196), 256, 0, stream>>>(x, q_w, nullptr, qbuf, 12544, 512, 512);
    // 7) attention -> scr (reused as [B*N,512])
    attn_k<<<dim3(49, 8, 4), 64, 0, stream>>>(qbuf, kvp, scr);
    // 8) output projection (+bias): [12544,512]@[512,512] -> out
    gemm64<<<dim3(8, 196), 256, 0, stream>>>(scr, pj_w, pj_b, out, 12544, 512, 512);
}